// Round 15
// baseline (160.686 us; speedup 1.0000x reference)
//
#include <hip/hip_runtime.h>
#include <hip/hip_bf16.h>
#include <stdint.h>

#define C_DIM 256
#define N_DIM 4096
#define B_DIM 4

typedef __attribute__((ext_vector_type(8))) short s16x8;   // 8 bf16
typedef __attribute__((ext_vector_type(4))) short s16x4;   // 4 bf16
typedef __attribute__((ext_vector_type(4))) float f32x4;
typedef __attribute__((ext_vector_type(16))) float f32x16;
typedef __attribute__((ext_vector_type(4))) int i32x4;

static __device__ __forceinline__ short f2bs(float f) {
    __bf16 h = (__bf16)f;                 // RNE f32->bf16
    return __builtin_bit_cast(short, h);
}
static __device__ __forceinline__ float bs2f(short s) {
    unsigned int u = ((unsigned int)(unsigned short)s) << 16;
    return __builtin_bit_cast(float, u);
}
static __device__ __forceinline__ unsigned cvtpk(float lo, float hi) {
    unsigned r;
    asm("v_cvt_pk_bf16_f32 %0, %1, %2" : "=v"(r) : "v"(lo), "v"(hi));
    return r;
}
// v_permlane32_swap_b32: a' = {a.lo32lanes, b.lo32lanes}; b' = {a.hi, b.hi}
static __device__ __forceinline__ void plswap(unsigned &a, unsigned &b) {
    asm("v_permlane32_swap_b32 %0, %1" : "+v"(a), "+v"(b));
}

// ---------------------------------------------------------------------------
// Kernel 1 (prep fused): projections directly from f32 x/y + f32 weights.
// Grid 768 = 64 nt x 4 b x 3 p; per block: transpose-stage the 64n x 256c
// src tile into Xs (two-phase T[64][66] transpose, conflict-free), then
// loop ot=0..3 { stage f32 weight tile -> Ws bf16; MFMA; write }.
// Qb,Kb = [B][N][256]; Vb = [B][256][N]; Q pre-scaled by log2(e).
// ---------------------------------------------------------------------------
__global__ __launch_bounds__(256)
void proj_kernel(const float* __restrict__ x, const float* __restrict__ y,
                 const float* __restrict__ wq, const float* __restrict__ wk,
                 const float* __restrict__ wv,
                 short* __restrict__ Qb, short* __restrict__ Kb,
                 short* __restrict__ Vb)
{
    int bid = blockIdx.x;              // 768 = 64 nt x 4 b x 3 p
    int nt = bid & 63;
    int b  = (bid >> 6) & 3;
    int p  = bid >> 8;                 // 0:Q(x) 1:K(y) 2:V(y)
    int n0 = nt * 64;
    const float* src = (p == 0) ? x : y;
    const float* w   = (p == 0) ? wq : (p == 1) ? wk : wv;

    __shared__ __align__(16) short Xs[64][264];   // 33.8 KB
    __shared__ __align__(16) short Ws[64][264];   // 33.8 KB
    __shared__ short T[64][66];                   //  8.4 KB -> 76 KB total

    int t = threadIdx.x;
    int l = t & 63;
    int wv_ = t >> 6;

    // ---- stage + transpose src: f32 [C][N]-tile -> Xs[n][c] bf16 --------
    for (int ct = 0; ct < 4; ++ct) {
        #pragma unroll
        for (int pp = 0; pp < 16; ++pp) {
            int c = wv_ + pp * 4;
            float v = src[((size_t)(b * C_DIM + ct * 64 + c)) * N_DIM + n0 + l];
            T[l][c] = f2bs(v);         // [66] stride: conflict-free col write
        }
        __syncthreads();
        #pragma unroll
        for (int pp = 0; pp < 16; ++pp) {
            int n = wv_ + pp * 4;
            Xs[n][ct * 64 + l] = T[n][l];  // row-major write, conflict-free
        }
        __syncthreads();               // also guards T reuse next ct
    }

    int lane = t & 63;
    int wid = t >> 6;
    int m = lane & 15, q = lane >> 4;

    for (int ot = 0; ot < 4; ++ot) {
        int o0 = ot * 64;
        // ---- stage weight tile: f32 -> bf16, coalesced row-major --------
        #pragma unroll
        for (int pas = 0; pas < 8; ++pas) {
            int slot = pas * 256 + t;
            int row = slot >> 5, ck = slot & 31;
            const float* wr = &w[(size_t)(o0 + row) * C_DIM + ck * 8];
            f32x4 a  = *(const f32x4*)wr;
            f32x4 b4 = *(const f32x4*)(wr + 4);
            s16x8 r;
            r[0]=f2bs(a[0]);  r[1]=f2bs(a[1]);  r[2]=f2bs(a[2]);  r[3]=f2bs(a[3]);
            r[4]=f2bs(b4[0]); r[5]=f2bs(b4[1]); r[6]=f2bs(b4[2]); r[7]=f2bs(b4[3]);
            *(s16x8*)&Ws[row][ck * 8] = r;
        }
        __syncthreads();

        f32x4 acc[4] = {};
        if (p < 2) {
            #pragma unroll
            for (int kk = 0; kk < 8; ++kk) {
                s16x8 af = *(const s16x8*)&Xs[wid * 16 + m][kk * 32 + q * 8];
                #pragma unroll
                for (int ob = 0; ob < 4; ++ob) {
                    s16x8 bf = *(const s16x8*)&Ws[ob * 16 + m][kk * 32 + q * 8];
                    acc[ob] = __builtin_amdgcn_mfma_f32_16x16x32_bf16(af, bf, acc[ob], 0, 0, 0);
                }
            }
            float sc = (p == 0) ? 1.4426950408889634f : 1.0f;  // log2(e) for Q
            short* dst = ((p == 0) ? Qb : Kb) + (size_t)b * N_DIM * C_DIM;
            #pragma unroll
            for (int ob = 0; ob < 4; ++ob)
                #pragma unroll
                for (int r = 0; r < 4; ++r) {
                    int n = n0 + wid * 16 + q * 4 + r;
                    int o = o0 + ob * 16 + m;
                    dst[(size_t)n * C_DIM + o] = f2bs(acc[ob][r] * sc);
                }
        } else {
            #pragma unroll
            for (int kk = 0; kk < 8; ++kk) {
                s16x8 af = *(const s16x8*)&Ws[wid * 16 + m][kk * 32 + q * 8];
                #pragma unroll
                for (int nb = 0; nb < 4; ++nb) {
                    s16x8 bf = *(const s16x8*)&Xs[nb * 16 + m][kk * 32 + q * 8];
                    acc[nb] = __builtin_amdgcn_mfma_f32_16x16x32_bf16(af, bf, acc[nb], 0, 0, 0);
                }
            }
            short* dst = Vb + (size_t)b * C_DIM * N_DIM;
            #pragma unroll
            for (int nb = 0; nb < 4; ++nb)
                #pragma unroll
                for (int r = 0; r < 4; ++r) {
                    int o = o0 + wid * 16 + q * 4 + r;
                    int n = n0 + nb * 16 + m;
                    dst[(size_t)o * N_DIM + n] = f2bs(acc[nb][r]);
                }
        }
        __syncthreads();   // Ws reads done before next ot overwrites
    }
}

// ---------------------------------------------------------------------------
// Kernel 2: WAVE-INDEPENDENT flash attention, ksplit=4, CONSTANT-SHIFT
// softmax. vs R13 (isolated change): BOTH K and V double-buffered in their
// PROVEN PADDED layouts (Ksh[2][32][264], Vsh[2][256][40] = 74.8 KB, still
// 2 blocks/CU), reg-staged as before — NO DMA, NO layout change (R14's
// regression was the K-DMA linear layout: conflicts 3x). Stage-writes go to
// buffer nx while reads hit cur -> ONE barrier per jt (R13 had two).
// Global loads issued at loop top -> latency hides under QK+softmax.
// P = exp2(S - 64); partials: ks 0/1 -> Op01; ks 2/3 packed in out's f32
// slots. merge_kernel normalizes.
// ---------------------------------------------------------------------------
__global__ __launch_bounds__(256, 2)
void attn_kernel(const short* __restrict__ Qb, const short* __restrict__ Kb,
                 const short* __restrict__ Vb,
                 short* __restrict__ Op01, short* __restrict__ Op23,
                 float* __restrict__ ms)
{
    int bid0 = blockIdx.x;
    int swz = (bid0 & 7) * 64 + (bid0 >> 3);   // XCD swizzle: 64 blocks/XCD
    int b  = swz >> 7;                          // share one (b, 2 ks) K/V set
    int ks = (swz >> 5) & 3;
    int qt = swz & 31;
    int i0 = qt * 128;

    int t = threadIdx.x;
    int wv = t >> 6;
    int lane = t & 63;
    int il = lane & 31, hi = lane >> 5;
    int q0 = i0 + wv * 32;

    __shared__ __align__(16) short Ksh[2][32][264];   // 33.8 KB, padded
    __shared__ __align__(16) short Vsh[2][256][40];   // 41.0 KB, padded

    const short* Qp = Qb + (size_t)b * N_DIM * C_DIM;
    const short* Kp = Kb + (size_t)b * N_DIM * C_DIM + (size_t)(ks * 1024) * C_DIM;
    const short* Vp = Vb + (size_t)b * C_DIM * N_DIM + ks * 1024;

    // Q fragments: B[k=c][col=q], lane holds q = q0+il, c = kk*16+hi*8+e
    s16x8 qf[16];
    {
        const short* qrow = Qp + (size_t)(q0 + il) * C_DIM + hi * 8;
        #pragma unroll
        for (int kk = 0; kk < 16; ++kk)
            qf[kk] = *(const s16x8*)&qrow[kk * 16];
    }

    // staging maps (256 threads): K tile 32x256, V tile 256x32, 4x16B each
    int krb = t >> 5, kck = t & 31;   // K rows p*8+krb
    int vrb = t >> 2, vck = t & 3;    // V rows p*64+vrb

    // prologue: stage tile 0 into buffer 0
    {
        s16x8 kr[4], vr[4];
        #pragma unroll
        for (int p = 0; p < 4; ++p)
            kr[p] = *(const s16x8*)&Kp[(size_t)(p * 8 + krb) * C_DIM + kck * 8];
        #pragma unroll
        for (int p = 0; p < 4; ++p)
            vr[p] = *(const s16x8*)&Vp[(size_t)(p * 64 + vrb) * N_DIM + vck * 8];
        #pragma unroll
        for (int p = 0; p < 4; ++p) *(s16x8*)&Ksh[0][p * 8 + krb][kck * 8] = kr[p];
        #pragma unroll
        for (int p = 0; p < 4; ++p) *(s16x8*)&Vsh[0][p * 64 + vrb][vck * 8] = vr[p];
    }
    __syncthreads();

    f32x16 acc[8] = {};               // O^T[c = cs*32+crow(r,hi)][q = il]
    float srun = 0.f;                 // per-lane partial; reduced in epilogue

    for (int jt = 0; jt < 32; ++jt) {
        bool pfch = (jt < 31);
        int cur = jt & 1, nx = cur ^ 1;

        // ---- issue K+V global loads for jt+1 (latency under QK+softmax) --
        s16x8 kr[4], vr[4];
        if (pfch) {
            const short* kg = Kp + (size_t)((jt + 1) * 32) * C_DIM;
            #pragma unroll
            for (int p = 0; p < 4; ++p)
                kr[p] = *(const s16x8*)&kg[(size_t)(p * 8 + krb) * C_DIM + kck * 8];
            const short* vg = Vp + (jt + 1) * 32;
            #pragma unroll
            for (int p = 0; p < 4; ++p)
                vr[p] = *(const s16x8*)&vg[(size_t)(p * 64 + vrb) * N_DIM + vck * 8];
        }

        // ---- QK: 2 independent 8-chains ---------------------------------
        f32x16 sv0 = {}, sv1 = {};
        __builtin_amdgcn_s_setprio(1);
        #pragma unroll
        for (int kk = 0; kk < 8; ++kk) {
            s16x8 a0 = *(const s16x8*)&Ksh[cur][il][kk * 16 + hi * 8];
            sv0 = __builtin_amdgcn_mfma_f32_32x32x16_bf16(a0, qf[kk], sv0, 0, 0, 0);
            s16x8 a1 = *(const s16x8*)&Ksh[cur][il][(kk + 8) * 16 + hi * 8];
            sv1 = __builtin_amdgcn_mfma_f32_32x32x16_bf16(a1, qf[kk + 8], sv1, 0, 0, 0);
        }
        __builtin_amdgcn_s_setprio(0);

        // ---- constant-shift softmax: no max, no rescale, no cross-lane --
        #pragma unroll
        for (int r = 0; r < 16; ++r) {
            float pe = exp2f((sv0[r] + sv1[r]) - 64.f);  // Q pre-scaled log2e
            sv0[r] = pe;
            srun += pe;
        }

        // ---- P -> bf16 PV B-fragments (cvt_pk + permlane32_swap) --------
        unsigned d0[4], d1[4];
        #pragma unroll
        for (int rq = 0; rq < 4; ++rq) {
            d0[rq] = cvtpk(sv0[4 * rq + 0], sv0[4 * rq + 1]);
            d1[rq] = cvtpk(sv0[4 * rq + 2], sv0[4 * rq + 3]);
        }
        unsigned w0a = d0[0], w2a = d0[1]; plswap(w0a, w2a);
        unsigned w1a = d1[0], w3a = d1[1]; plswap(w1a, w3a);
        unsigned w0b = d0[2], w2b = d0[3]; plswap(w0b, w2b);
        unsigned w1b = d1[2], w3b = d1[3]; plswap(w1b, w3b);
        i32x4 pi0 = { (int)w0a, (int)w1a, (int)w2a, (int)w3a };
        i32x4 pi1 = { (int)w0b, (int)w1b, (int)w2b, (int)w3b };
        s16x8 pf0 = __builtin_bit_cast(s16x8, pi0);   // keys 0..15 of tile
        s16x8 pf1 = __builtin_bit_cast(s16x8, pi1);   // keys 16..31

        // ---- stage K(jt+1)+V(jt+1) into buffer nx (no reader this jt) ---
        if (pfch) {
            #pragma unroll
            for (int p = 0; p < 4; ++p) *(s16x8*)&Ksh[nx][p * 8 + krb][kck * 8] = kr[p];
            #pragma unroll
            for (int p = 0; p < 4; ++p) *(s16x8*)&Vsh[nx][p * 64 + vrb][vck * 8] = vr[p];
        }

        // ---- PV: 8 c-strips x 2 k-slices, 8 independent acc chains ------
        __builtin_amdgcn_s_setprio(1);
        #pragma unroll
        for (int cs = 0; cs < 8; ++cs) {
            s16x8 va = *(const s16x8*)&Vsh[cur][cs * 32 + il][hi * 8];
            acc[cs] = __builtin_amdgcn_mfma_f32_32x32x16_bf16(va, pf0, acc[cs], 0, 0, 0);
            s16x8 vb = *(const s16x8*)&Vsh[cur][cs * 32 + il][16 + hi * 8];
            acc[cs] = __builtin_amdgcn_mfma_f32_32x32x16_bf16(vb, pf1, acc[cs], 0, 0, 0);
        }
        __builtin_amdgcn_s_setprio(0);

        __syncthreads();   // single barrier: cur reads done + nx fully staged
    }

    // ---- epilogue: reduce srun once; unnormalized O^T partial + s -------
    srun += __shfl_xor(srun, 32, 64);
    int i = q0 + il;
    const size_t HSZ = (size_t)B_DIM * C_DIM * N_DIM;
    if (ks < 2) {
        short* o = Op01 + (size_t)ks * HSZ + (size_t)(b * C_DIM) * N_DIM + i;
        #pragma unroll
        for (int cs = 0; cs < 8; ++cs)
            #pragma unroll
            for (int r = 0; r < 16; ++r) {
                int c = cs * 32 + (r & 3) + 8 * (r >> 2) + 4 * hi;
                o[(size_t)c * N_DIM] = f2bs(acc[cs][r]);
            }
    } else {
        // pack as bf16 pair inside out's f32 slot: [2*idx + (ks-2)]
        short* o = Op23 + ((size_t)(b * C_DIM) * N_DIM + i) * 2 + (ks - 2);
        #pragma unroll
        for (int cs = 0; cs < 8; ++cs)
            #pragma unroll
            for (int r = 0; r < 16; ++r) {
                int c = cs * 32 + (r & 3) + 8 * (r >> 2) + 4 * hi;
                o[(size_t)c * N_DIM * 2] = f2bs(acc[cs][r]);
            }
    }
    if (hi == 0) {
        float* msp = ms + (size_t)(ks * B_DIM + b) * N_DIM;
        msp[i] = srun;
    }
}

// ---------------------------------------------------------------------------
// Kernel 3: 4-way merge + gamma/residual epilogue. All partials share the
// same shift (64) -> plain sums: out = g * (sum O_h) / (sum s_h) + x.
// Op2/3 are read from out's own f32 slots (interleaved bf16) and then the
// slot is overwritten by the SAME thread -> race-free.
// ---------------------------------------------------------------------------
__global__ __launch_bounds__(256)
void merge_kernel(const short* __restrict__ Op01, const short* Op23,
                  const float* __restrict__ ms, const float* __restrict__ x,
                  const float* __restrict__ gamma, float* out)
{
    size_t base = ((size_t)blockIdx.x * 256 + threadIdx.x) * 8;
    int n = (int)(base & (N_DIM - 1));
    int b = (int)(base >> 20);                     // 256*4096 = 2^20 per batch
    const size_t HSZ = (size_t)B_DIM * C_DIM * N_DIM;

    s16x8 o0 = *(const s16x8*)&Op01[base];
    s16x8 o1 = *(const s16x8*)&Op01[HSZ + base];
    s16x8 pa = *(const s16x8*)&Op23[base * 2];      // n..n+3 (o2,o3 pairs)
    s16x8 pb = *(const s16x8*)&Op23[base * 2 + 8];  // n+4..n+7

    f32x4 den[2] = {};
    #pragma unroll
    for (int h = 0; h < 4; ++h) {
        const float* msp = ms + (size_t)(h * B_DIM + b) * N_DIM + n;
        f32x4 sa = *(const f32x4*)&msp[0];
        f32x4 sb = *(const f32x4*)&msp[4];
        #pragma unroll
        for (int e = 0; e < 4; ++e) { den[0][e] += sa[e]; den[1][e] += sb[e]; }
    }
    f32x4 xa = *(const f32x4*)&x[base];
    f32x4 xb = *(const f32x4*)&x[base + 4];
    float g = gamma[0];

    float res[8];
    #pragma unroll
    for (int e = 0; e < 8; ++e) {
        int half = e >> 2, e4 = e & 3;
        float o2 = bs2f(e < 4 ? pa[2 * e]     : pb[2 * (e - 4)]);
        float o3 = bs2f(e < 4 ? pa[2 * e + 1] : pb[2 * (e - 4) + 1]);
        float num = bs2f(o0[e]) + bs2f(o1[e]) + o2 + o3;
        float xv = (e < 4) ? xa[e4] : xb[e4];
        res[e] = g * (num / den[half][e4]) + xv;
    }
    f32x4 ra = { res[0], res[1], res[2], res[3] };
    f32x4 rb = { res[4], res[5], res[6], res[7] };
    *(f32x4*)&out[base] = ra;
    *(f32x4*)&out[base + 4] = rb;
}

// ---------------------------------------------------------------------------
extern "C" void kernel_launch(void* const* d_in, const int* in_sizes, int n_in,
                              void* d_out, int out_size, void* d_ws, size_t ws_size,
                              hipStream_t stream) {
    const float* x  = (const float*)d_in[0];
    const float* y  = (const float*)d_in[1];
    const float* wq = (const float*)d_in[2];
    const float* wk = (const float*)d_in[3];
    const float* wv = (const float*)d_in[4];
    const float* gm = (const float*)d_in[5];
    float* out = (float*)d_out;

    char* ws = (char*)d_ws;
    const size_t SZ = (size_t)B_DIM * N_DIM * C_DIM * sizeof(short); // 8 MB
    short* Qb = (short*)(ws + 2 * SZ);
    short* Kb = (short*)(ws + 3 * SZ);
    short* Vb = (short*)(ws + 4 * SZ);
    // overlays: Op01 -> first 2*SZ of ws (16.8 MB scratch);
    // ms -> ws + 5*SZ (256 KB)
    short* Op01 = (short*)ws;
    float* ms = (float*)(ws + 5 * SZ);

    proj_kernel<<<dim3(768), dim3(256), 0, stream>>>(x, y, wq, wk, wv, Qb, Kb, Vb);
    attn_kernel<<<dim3(512), dim3(256), 0, stream>>>(Qb, Kb, Vb, Op01, (short*)out, ms);
    merge_kernel<<<dim3(2048), dim3(256), 0, stream>>>(Op01, (const short*)out, ms, x, gm, out);
}

// Round 16
// 124.668 us; speedup vs baseline: 1.2889x; 1.2889x over previous
//
#include <hip/hip_runtime.h>
#include <hip/hip_bf16.h>
#include <stdint.h>

#define C_DIM 256
#define N_DIM 4096
#define B_DIM 4

typedef __attribute__((ext_vector_type(8))) short s16x8;   // 8 bf16
typedef __attribute__((ext_vector_type(4))) short s16x4;   // 4 bf16
typedef __attribute__((ext_vector_type(4))) float f32x4;
typedef __attribute__((ext_vector_type(16))) float f32x16;
typedef __attribute__((ext_vector_type(4))) int i32x4;

static __device__ __forceinline__ short f2bs(float f) {
    __bf16 h = (__bf16)f;                 // RNE f32->bf16
    return __builtin_bit_cast(short, h);
}
static __device__ __forceinline__ float bs2f(short s) {
    unsigned int u = ((unsigned int)(unsigned short)s) << 16;
    return __builtin_bit_cast(float, u);
}
static __device__ __forceinline__ unsigned cvtpk(float lo, float hi) {
    unsigned r;
    asm("v_cvt_pk_bf16_f32 %0, %1, %2" : "=v"(r) : "v"(lo), "v"(hi));
    return r;
}
// v_permlane32_swap_b32: a' = {a.lo32lanes, b.lo32lanes}; b' = {a.hi, b.hi}
static __device__ __forceinline__ void plswap(unsigned &a, unsigned &b) {
    asm("v_permlane32_swap_b32 %0, %1" : "+v"(a), "+v"(b));
}

// ---------------------------------------------------------------------------
// Kernel 1 (prep fused): projections directly from f32 x/y + f32 weights.
// Grid 512 = 64 nt x 4 b x 2 g. g=0: Q from x. g=1: BOTH K and V from one
// staged y tile (y read ONCE; the old 3-p grid read it twice). Per block:
// transpose-stage src tile into Xs (two-phase T[64][66], conflict-free),
// then per ot: stage f32 weight tile -> Ws bf16, MFMA, write. g=1 runs two
// weight sub-phases (wk then wv) per ot.
// Qb,Kb = [B][N][256]; Vb = [B][256][N]; Q pre-scaled by log2(e).
// ---------------------------------------------------------------------------
__global__ __launch_bounds__(256)
void proj_kernel(const float* __restrict__ x, const float* __restrict__ y,
                 const float* __restrict__ wq, const float* __restrict__ wk,
                 const float* __restrict__ wv,
                 short* __restrict__ Qb, short* __restrict__ Kb,
                 short* __restrict__ Vb)
{
    int bid = blockIdx.x;              // 512 = 64 nt x 4 b x 2 g
    int nt = bid & 63;
    int b  = (bid >> 6) & 3;
    int g  = bid >> 8;                 // 0: Q(x)   1: K+V(y)
    int n0 = nt * 64;
    const float* src = (g == 0) ? x : y;

    __shared__ __align__(16) short Xs[64][264];   // 33.8 KB
    __shared__ __align__(16) short Ws[64][264];   // 33.8 KB
    __shared__ short T[64][66];                   //  8.4 KB -> 76 KB total

    int t = threadIdx.x;
    int l = t & 63;
    int wv_ = t >> 6;

    // ---- stage + transpose src: f32 [C][N]-tile -> Xs[n][c] bf16 --------
    for (int ct = 0; ct < 4; ++ct) {
        #pragma unroll
        for (int pp = 0; pp < 16; ++pp) {
            int c = wv_ + pp * 4;
            float v = src[((size_t)(b * C_DIM + ct * 64 + c)) * N_DIM + n0 + l];
            T[l][c] = f2bs(v);         // [66] stride: conflict-free col write
        }
        __syncthreads();
        #pragma unroll
        for (int pp = 0; pp < 16; ++pp) {
            int n = wv_ + pp * 4;
            Xs[n][ct * 64 + l] = T[n][l];  // row-major write, conflict-free
        }
        __syncthreads();               // also guards T reuse next ct
    }

    int lane = t & 63;
    int wid = t >> 6;
    int m = lane & 15, q = lane >> 4;

    for (int ot = 0; ot < 4; ++ot) {
        int o0 = ot * 64;
        int nsub = (g == 0) ? 1 : 2;
        for (int sub = 0; sub < nsub; ++sub) {
            const float* w = (g == 0) ? wq : (sub == 0) ? wk : wv;
            // ---- stage weight tile: f32 -> bf16, coalesced row-major ----
            #pragma unroll
            for (int pas = 0; pas < 8; ++pas) {
                int slot = pas * 256 + t;
                int row = slot >> 5, ck = slot & 31;
                const float* wr = &w[(size_t)(o0 + row) * C_DIM + ck * 8];
                f32x4 a  = *(const f32x4*)wr;
                f32x4 b4 = *(const f32x4*)(wr + 4);
                s16x8 r;
                r[0]=f2bs(a[0]);  r[1]=f2bs(a[1]);  r[2]=f2bs(a[2]);  r[3]=f2bs(a[3]);
                r[4]=f2bs(b4[0]); r[5]=f2bs(b4[1]); r[6]=f2bs(b4[2]); r[7]=f2bs(b4[3]);
                *(s16x8*)&Ws[row][ck * 8] = r;
            }
            __syncthreads();

            f32x4 acc[4] = {};
            bool qk_path = (g == 0) || (sub == 0);   // Q or K: [N][C] output
            if (qk_path) {
                #pragma unroll
                for (int kk = 0; kk < 8; ++kk) {
                    s16x8 af = *(const s16x8*)&Xs[wid * 16 + m][kk * 32 + q * 8];
                    #pragma unroll
                    for (int ob = 0; ob < 4; ++ob) {
                        s16x8 bf = *(const s16x8*)&Ws[ob * 16 + m][kk * 32 + q * 8];
                        acc[ob] = __builtin_amdgcn_mfma_f32_16x16x32_bf16(af, bf, acc[ob], 0, 0, 0);
                    }
                }
                float sc = (g == 0) ? 1.4426950408889634f : 1.0f;  // log2(e) for Q
                short* dst = ((g == 0) ? Qb : Kb) + (size_t)b * N_DIM * C_DIM;
                #pragma unroll
                for (int ob = 0; ob < 4; ++ob)
                    #pragma unroll
                    for (int r = 0; r < 4; ++r) {
                        int n = n0 + wid * 16 + q * 4 + r;
                        int o = o0 + ob * 16 + m;
                        dst[(size_t)n * C_DIM + o] = f2bs(acc[ob][r] * sc);
                    }
            } else {
                #pragma unroll
                for (int kk = 0; kk < 8; ++kk) {
                    s16x8 af = *(const s16x8*)&Ws[wid * 16 + m][kk * 32 + q * 8];
                    #pragma unroll
                    for (int nb = 0; nb < 4; ++nb) {
                        s16x8 bf = *(const s16x8*)&Xs[nb * 16 + m][kk * 32 + q * 8];
                        acc[nb] = __builtin_amdgcn_mfma_f32_16x16x32_bf16(af, bf, acc[nb], 0, 0, 0);
                    }
                }
                short* dst = Vb + (size_t)b * C_DIM * N_DIM;
                #pragma unroll
                for (int nb = 0; nb < 4; ++nb)
                    #pragma unroll
                    for (int r = 0; r < 4; ++r) {
                        int o = o0 + wid * 16 + q * 4 + r;
                        int n = n0 + nb * 16 + m;
                        dst[(size_t)o * N_DIM + n] = f2bs(acc[nb][r]);
                    }
            }
            __syncthreads();   // Ws reads done before next stage overwrites
        }
    }
}

// ---------------------------------------------------------------------------
// Kernel 2: WAVE-INDEPENDENT flash attention, ksplit=4, CONSTANT-SHIFT
// softmax (R13 verbatim — best measured: attn 92.4 us; FROZEN).
// Grid 512 x 256thr (4 waves), 2 blocks/CU (256 unified regs/wave = cap).
// P = exp2(S - 64); no max tracking, no cross-lane ops in the P-path.
// The 2-barrier, late-prefetch schedule is the ONLY variant that fits the
// register budget (R14: DMA-linear -> 3x bank conflicts; R15: hoisted
// loads -> spill; both regressed ~40 us). Do not touch.
// Partials: ks 0/1 -> Op01; ks 2/3 packed in out's f32 slots.
// ---------------------------------------------------------------------------
__global__ __launch_bounds__(256, 2)
void attn_kernel(const short* __restrict__ Qb, const short* __restrict__ Kb,
                 const short* __restrict__ Vb,
                 short* __restrict__ Op01, short* __restrict__ Op23,
                 float* __restrict__ ms)
{
    int bid0 = blockIdx.x;
    int swz = (bid0 & 7) * 64 + (bid0 >> 3);   // XCD swizzle: 64 blocks/XCD
    int b  = swz >> 7;                          // share one (b, 2 ks) K/V set
    int ks = (swz >> 5) & 3;
    int qt = swz & 31;
    int i0 = qt * 128;

    int t = threadIdx.x;
    int wv = t >> 6;
    int lane = t & 63;
    int il = lane & 31, hi = lane >> 5;
    int q0 = i0 + wv * 32;

    __shared__ __align__(16) short Ksh[32][264];   // 16.9 KB
    __shared__ __align__(16) short Vsh[256][40];   // 20.5 KB

    const short* Qp = Qb + (size_t)b * N_DIM * C_DIM;
    const short* Kp = Kb + (size_t)b * N_DIM * C_DIM + (size_t)(ks * 1024) * C_DIM;
    const short* Vp = Vb + (size_t)b * C_DIM * N_DIM + ks * 1024;

    // Q fragments: B[k=c][col=q], lane holds q = q0+il, c = kk*16+hi*8+e
    s16x8 qf[16];
    {
        const short* qrow = Qp + (size_t)(q0 + il) * C_DIM + hi * 8;
        #pragma unroll
        for (int kk = 0; kk < 16; ++kk)
            qf[kk] = *(const s16x8*)&qrow[kk * 16];
    }

    // staging maps (256 threads): K tile 32x256, V tile 256x32, 4x16B each
    int krb = t >> 5, kck = t & 31;   // K rows p*8+krb
    int vrb = t >> 2, vck = t & 3;    // V rows p*64+vrb

    // prologue: stage tile 0
    {
        s16x8 kr[4], vr[4];
        #pragma unroll
        for (int p = 0; p < 4; ++p)
            kr[p] = *(const s16x8*)&Kp[(size_t)(p * 8 + krb) * C_DIM + kck * 8];
        #pragma unroll
        for (int p = 0; p < 4; ++p)
            vr[p] = *(const s16x8*)&Vp[(size_t)(p * 64 + vrb) * N_DIM + vck * 8];
        #pragma unroll
        for (int p = 0; p < 4; ++p) *(s16x8*)&Ksh[p * 8 + krb][kck * 8] = kr[p];
        #pragma unroll
        for (int p = 0; p < 4; ++p) *(s16x8*)&Vsh[p * 64 + vrb][vck * 8] = vr[p];
    }
    __syncthreads();

    f32x16 acc[8] = {};               // O^T[c = cs*32+crow(r,hi)][q = il]
    float srun = 0.f;                 // per-lane partial; reduced in epilogue

    for (int jt = 0; jt < 32; ++jt) {
        bool pfch = (jt < 31);

        // ---- QK: 2 independent 8-chains --------------------------------
        f32x16 sv0 = {}, sv1 = {};
        __builtin_amdgcn_s_setprio(1);
        #pragma unroll
        for (int kk = 0; kk < 8; ++kk) {
            s16x8 a0 = *(const s16x8*)&Ksh[il][kk * 16 + hi * 8];
            sv0 = __builtin_amdgcn_mfma_f32_32x32x16_bf16(a0, qf[kk], sv0, 0, 0, 0);
            s16x8 a1 = *(const s16x8*)&Ksh[il][(kk + 8) * 16 + hi * 8];
            sv1 = __builtin_amdgcn_mfma_f32_32x32x16_bf16(a1, qf[kk + 8], sv1, 0, 0, 0);
        }
        __builtin_amdgcn_s_setprio(0);

        // issue K prefetch (latency hides under softmax+PV)
        s16x8 kr[4];
        if (pfch) {
            const short* kg = Kp + (size_t)((jt + 1) * 32) * C_DIM;
            #pragma unroll
            for (int p = 0; p < 4; ++p)
                kr[p] = *(const s16x8*)&kg[(size_t)(p * 8 + krb) * C_DIM + kck * 8];
        }

        // ---- constant-shift softmax: no max, no rescale, no cross-lane --
        #pragma unroll
        for (int r = 0; r < 16; ++r) {
            float pe = exp2f((sv0[r] + sv1[r]) - 64.f);  // Q pre-scaled log2e
            sv0[r] = pe;
            srun += pe;
        }

        // ---- P -> bf16 PV B-fragments (cvt_pk + permlane32_swap) --------
        unsigned d0[4], d1[4];
        #pragma unroll
        for (int rq = 0; rq < 4; ++rq) {
            d0[rq] = cvtpk(sv0[4 * rq + 0], sv0[4 * rq + 1]);
            d1[rq] = cvtpk(sv0[4 * rq + 2], sv0[4 * rq + 3]);
        }
        unsigned w0a = d0[0], w2a = d0[1]; plswap(w0a, w2a);
        unsigned w1a = d1[0], w3a = d1[1]; plswap(w1a, w3a);
        unsigned w0b = d0[2], w2b = d0[3]; plswap(w0b, w2b);
        unsigned w1b = d1[2], w3b = d1[3]; plswap(w1b, w3b);
        i32x4 pi0 = { (int)w0a, (int)w1a, (int)w2a, (int)w3a };
        i32x4 pi1 = { (int)w0b, (int)w1b, (int)w2b, (int)w3b };
        s16x8 pf0 = __builtin_bit_cast(s16x8, pi0);   // keys 0..15 of tile
        s16x8 pf1 = __builtin_bit_cast(s16x8, pi1);   // keys 16..31

        // issue V prefetch
        s16x8 vr[4];
        if (pfch) {
            const short* vg = Vp + (jt + 1) * 32;
            #pragma unroll
            for (int p = 0; p < 4; ++p)
                vr[p] = *(const s16x8*)&vg[(size_t)(p * 64 + vrb) * N_DIM + vck * 8];
        }

        // ---- PV: 8 c-strips x 2 k-slices, 8 independent acc chains ------
        __builtin_amdgcn_s_setprio(1);
        #pragma unroll
        for (int cs = 0; cs < 8; ++cs) {
            s16x8 va = *(const s16x8*)&Vsh[cs * 32 + il][hi * 8];
            acc[cs] = __builtin_amdgcn_mfma_f32_32x32x16_bf16(va, pf0, acc[cs], 0, 0, 0);
            s16x8 vb = *(const s16x8*)&Vsh[cs * 32 + il][16 + hi * 8];
            acc[cs] = __builtin_amdgcn_mfma_f32_32x32x16_bf16(vb, pf1, acc[cs], 0, 0, 0);
        }
        __builtin_amdgcn_s_setprio(0);

        __syncthreads();                 // all reads of tile jt done
        if (pfch) {
            #pragma unroll
            for (int p = 0; p < 4; ++p) *(s16x8*)&Ksh[p * 8 + krb][kck * 8] = kr[p];
            #pragma unroll
            for (int p = 0; p < 4; ++p) *(s16x8*)&Vsh[p * 64 + vrb][vck * 8] = vr[p];
        }
        __syncthreads();                 // tile jt+1 staged
    }

    // ---- epilogue: reduce srun once; unnormalized O^T partial + s -------
    srun += __shfl_xor(srun, 32, 64);
    int i = q0 + il;
    const size_t HSZ = (size_t)B_DIM * C_DIM * N_DIM;
    if (ks < 2) {
        short* o = Op01 + (size_t)ks * HSZ + (size_t)(b * C_DIM) * N_DIM + i;
        #pragma unroll
        for (int cs = 0; cs < 8; ++cs)
            #pragma unroll
            for (int r = 0; r < 16; ++r) {
                int c = cs * 32 + (r & 3) + 8 * (r >> 2) + 4 * hi;
                o[(size_t)c * N_DIM] = f2bs(acc[cs][r]);
            }
    } else {
        // pack as bf16 pair inside out's f32 slot: [2*idx + (ks-2)]
        short* o = Op23 + ((size_t)(b * C_DIM) * N_DIM + i) * 2 + (ks - 2);
        #pragma unroll
        for (int cs = 0; cs < 8; ++cs)
            #pragma unroll
            for (int r = 0; r < 16; ++r) {
                int c = cs * 32 + (r & 3) + 8 * (r >> 2) + 4 * hi;
                o[(size_t)c * N_DIM * 2] = f2bs(acc[cs][r]);
            }
    }
    if (hi == 0) {
        float* msp = ms + (size_t)(ks * B_DIM + b) * N_DIM;
        msp[i] = srun;
    }
}

// ---------------------------------------------------------------------------
// Kernel 3: 4-way merge + gamma/residual epilogue (R13 verbatim; BW-bound
// at ~67 MB traffic). All partials share shift 64 -> plain sums:
// out = g * (sum O_h) / (sum s_h) + x. Op2/3 are read from out's own f32
// slots and overwritten by the SAME thread -> race-free.
// ---------------------------------------------------------------------------
__global__ __launch_bounds__(256)
void merge_kernel(const short* __restrict__ Op01, const short* Op23,
                  const float* __restrict__ ms, const float* __restrict__ x,
                  const float* __restrict__ gamma, float* out)
{
    size_t base = ((size_t)blockIdx.x * 256 + threadIdx.x) * 8;
    int n = (int)(base & (N_DIM - 1));
    int b = (int)(base >> 20);                     // 256*4096 = 2^20 per batch
    const size_t HSZ = (size_t)B_DIM * C_DIM * N_DIM;

    s16x8 o0 = *(const s16x8*)&Op01[base];
    s16x8 o1 = *(const s16x8*)&Op01[HSZ + base];
    s16x8 pa = *(const s16x8*)&Op23[base * 2];      // n..n+3 (o2,o3 pairs)
    s16x8 pb = *(const s16x8*)&Op23[base * 2 + 8];  // n+4..n+7

    f32x4 den[2] = {};
    #pragma unroll
    for (int h = 0; h < 4; ++h) {
        const float* msp = ms + (size_t)(h * B_DIM + b) * N_DIM + n;
        f32x4 sa = *(const f32x4*)&msp[0];
        f32x4 sb = *(const f32x4*)&msp[4];
        #pragma unroll
        for (int e = 0; e < 4; ++e) { den[0][e] += sa[e]; den[1][e] += sb[e]; }
    }
    f32x4 xa = *(const f32x4*)&x[base];
    f32x4 xb = *(const f32x4*)&x[base + 4];
    float g = gamma[0];

    float res[8];
    #pragma unroll
    for (int e = 0; e < 8; ++e) {
        int half = e >> 2, e4 = e & 3;
        float o2 = bs2f(e < 4 ? pa[2 * e]     : pb[2 * (e - 4)]);
        float o3 = bs2f(e < 4 ? pa[2 * e + 1] : pb[2 * (e - 4) + 1]);
        float num = bs2f(o0[e]) + bs2f(o1[e]) + o2 + o3;
        float xv = (e < 4) ? xa[e4] : xb[e4];
        res[e] = g * (num / den[half][e4]) + xv;
    }
    f32x4 ra = { res[0], res[1], res[2], res[3] };
    f32x4 rb = { res[4], res[5], res[6], res[7] };
    *(f32x4*)&out[base] = ra;
    *(f32x4*)&out[base + 4] = rb;
}

// ---------------------------------------------------------------------------
extern "C" void kernel_launch(void* const* d_in, const int* in_sizes, int n_in,
                              void* d_out, int out_size, void* d_ws, size_t ws_size,
                              hipStream_t stream) {
    const float* x  = (const float*)d_in[0];
    const float* y  = (const float*)d_in[1];
    const float* wq = (const float*)d_in[2];
    const float* wk = (const float*)d_in[3];
    const float* wv = (const float*)d_in[4];
    const float* gm = (const float*)d_in[5];
    float* out = (float*)d_out;

    char* ws = (char*)d_ws;
    const size_t SZ = (size_t)B_DIM * N_DIM * C_DIM * sizeof(short); // 8 MB
    short* Qb = (short*)(ws + 2 * SZ);
    short* Kb = (short*)(ws + 3 * SZ);
    short* Vb = (short*)(ws + 4 * SZ);
    // overlays: Op01 -> first 2*SZ of ws (16.8 MB scratch);
    // ms -> ws + 5*SZ (256 KB)
    short* Op01 = (short*)ws;
    float* ms = (float*)(ws + 5 * SZ);

    proj_kernel<<<dim3(512), dim3(256), 0, stream>>>(x, y, wq, wk, wv, Qb, Kb, Vb);
    attn_kernel<<<dim3(512), dim3(256), 0, stream>>>(Qb, Kb, Vb, Op01, (short*)out, ms);
    merge_kernel<<<dim3(2048), dim3(256), 0, stream>>>(Op01, (const short*)out, ms, x, gm, out);
}

// Round 18
// 123.633 us; speedup vs baseline: 1.2997x; 1.0084x over previous
//
#include <hip/hip_runtime.h>
#include <hip/hip_bf16.h>
#include <stdint.h>

#define C_DIM 256
#define N_DIM 4096
#define B_DIM 4

typedef __attribute__((ext_vector_type(8))) short s16x8;   // 8 bf16
typedef __attribute__((ext_vector_type(4))) short s16x4;   // 4 bf16
typedef __attribute__((ext_vector_type(4))) float f32x4;
typedef __attribute__((ext_vector_type(16))) float f32x16;
typedef __attribute__((ext_vector_type(4))) int i32x4;

static __device__ __forceinline__ short f2bs(float f) {
    __bf16 h = (__bf16)f;                 // RNE f32->bf16
    return __builtin_bit_cast(short, h);
}
static __device__ __forceinline__ float bs2f(short s) {
    unsigned int u = ((unsigned int)(unsigned short)s) << 16;
    return __builtin_bit_cast(float, u);
}
static __device__ __forceinline__ unsigned cvtpk(float lo, float hi) {
    unsigned r;
    asm("v_cvt_pk_bf16_f32 %0, %1, %2" : "=v"(r) : "v"(lo), "v"(hi));
    return r;
}
// v_permlane32_swap_b32: a' = {a.lo32lanes, b.lo32lanes}; b' = {a.hi, b.hi}
static __device__ __forceinline__ void plswap(unsigned &a, unsigned &b) {
    asm("v_permlane32_swap_b32 %0, %1" : "+v"(a), "+v"(b));
}

// ---------------------------------------------------------------------------
// Kernel 1 (prep fused): projections directly from f32 x/y + f32 weights.
// Grid 512 = 64 nt x 4 b x 2 g. g=0: Q from x. g=1: BOTH K and V from one
// staged y tile (y read ONCE). Per block: transpose-stage src tile into Xs
// (two-phase T[64][66], conflict-free), then per ot: stage f32 weight tile
// -> Ws bf16, MFMA, write. g=1 runs two weight sub-phases (wk, wv) per ot.
// Qb,Kb = [B][N][256]; Vb = [B][256][N]; Q pre-scaled by log2(e).
// ---------------------------------------------------------------------------
__global__ __launch_bounds__(256)
void proj_kernel(const float* __restrict__ x, const float* __restrict__ y,
                 const float* __restrict__ wq, const float* __restrict__ wk,
                 const float* __restrict__ wv,
                 short* __restrict__ Qb, short* __restrict__ Kb,
                 short* __restrict__ Vb)
{
    int bid = blockIdx.x;              // 512 = 64 nt x 4 b x 2 g
    int nt = bid & 63;
    int b  = (bid >> 6) & 3;
    int g  = bid >> 8;                 // 0: Q(x)   1: K+V(y)
    int n0 = nt * 64;
    const float* src = (g == 0) ? x : y;

    __shared__ __align__(16) short Xs[64][264];   // 33.8 KB
    __shared__ __align__(16) short Ws[64][264];   // 33.8 KB
    __shared__ short T[64][66];                   //  8.4 KB -> 76 KB total

    int t = threadIdx.x;
    int l = t & 63;
    int wv_ = t >> 6;

    // ---- stage + transpose src: f32 [C][N]-tile -> Xs[n][c] bf16 --------
    for (int ct = 0; ct < 4; ++ct) {
        #pragma unroll
        for (int pp = 0; pp < 16; ++pp) {
            int c = wv_ + pp * 4;
            float v = src[((size_t)(b * C_DIM + ct * 64 + c)) * N_DIM + n0 + l];
            T[l][c] = f2bs(v);         // [66] stride: conflict-free col write
        }
        __syncthreads();
        #pragma unroll
        for (int pp = 0; pp < 16; ++pp) {
            int n = wv_ + pp * 4;
            Xs[n][ct * 64 + l] = T[n][l];  // row-major write, conflict-free
        }
        __syncthreads();               // also guards T reuse next ct
    }

    int lane = t & 63;
    int wid = t >> 6;
    int m = lane & 15, q = lane >> 4;

    for (int ot = 0; ot < 4; ++ot) {
        int o0 = ot * 64;
        int nsub = (g == 0) ? 1 : 2;
        for (int sub = 0; sub < nsub; ++sub) {
            const float* w = (g == 0) ? wq : (sub == 0) ? wk : wv;
            // ---- stage weight tile: f32 -> bf16, coalesced row-major ----
            #pragma unroll
            for (int pas = 0; pas < 8; ++pas) {
                int slot = pas * 256 + t;
                int row = slot >> 5, ck = slot & 31;
                const float* wr = &w[(size_t)(o0 + row) * C_DIM + ck * 8];
                f32x4 a  = *(const f32x4*)wr;
                f32x4 b4 = *(const f32x4*)(wr + 4);
                s16x8 r;
                r[0]=f2bs(a[0]);  r[1]=f2bs(a[1]);  r[2]=f2bs(a[2]);  r[3]=f2bs(a[3]);
                r[4]=f2bs(b4[0]); r[5]=f2bs(b4[1]); r[6]=f2bs(b4[2]); r[7]=f2bs(b4[3]);
                *(s16x8*)&Ws[row][ck * 8] = r;
            }
            __syncthreads();

            f32x4 acc[4] = {};
            bool qk_path = (g == 0) || (sub == 0);   // Q or K: [N][C] output
            if (qk_path) {
                #pragma unroll
                for (int kk = 0; kk < 8; ++kk) {
                    s16x8 af = *(const s16x8*)&Xs[wid * 16 + m][kk * 32 + q * 8];
                    #pragma unroll
                    for (int ob = 0; ob < 4; ++ob) {
                        s16x8 bf = *(const s16x8*)&Ws[ob * 16 + m][kk * 32 + q * 8];
                        acc[ob] = __builtin_amdgcn_mfma_f32_16x16x32_bf16(af, bf, acc[ob], 0, 0, 0);
                    }
                }
                float sc = (g == 0) ? 1.4426950408889634f : 1.0f;  // log2(e) for Q
                short* dst = ((g == 0) ? Qb : Kb) + (size_t)b * N_DIM * C_DIM;
                #pragma unroll
                for (int ob = 0; ob < 4; ++ob)
                    #pragma unroll
                    for (int r = 0; r < 4; ++r) {
                        int n = n0 + wid * 16 + q * 4 + r;
                        int o = o0 + ob * 16 + m;
                        dst[(size_t)n * C_DIM + o] = f2bs(acc[ob][r] * sc);
                    }
            } else {
                #pragma unroll
                for (int kk = 0; kk < 8; ++kk) {
                    s16x8 af = *(const s16x8*)&Ws[wid * 16 + m][kk * 32 + q * 8];
                    #pragma unroll
                    for (int nb = 0; nb < 4; ++nb) {
                        s16x8 bf = *(const s16x8*)&Xs[nb * 16 + m][kk * 32 + q * 8];
                        acc[nb] = __builtin_amdgcn_mfma_f32_16x16x32_bf16(af, bf, acc[nb], 0, 0, 0);
                    }
                }
                short* dst = Vb + (size_t)b * C_DIM * N_DIM;
                #pragma unroll
                for (int nb = 0; nb < 4; ++nb)
                    #pragma unroll
                    for (int r = 0; r < 4; ++r) {
                        int o = o0 + wid * 16 + q * 4 + r;
                        int n = n0 + nb * 16 + m;
                        dst[(size_t)o * N_DIM + n] = f2bs(acc[nb][r]);
                    }
            }
            __syncthreads();   // Ws reads done before next stage overwrites
        }
    }
}

// ---------------------------------------------------------------------------
// Kernel 2: WAVE-INDEPENDENT flash attention, ksplit=4, CONSTANT-SHIFT
// softmax (R13 verbatim — best measured: attn 92.3 us; FROZEN).
// Grid 512 x 256thr (4 waves), 2 blocks/CU (256 unified regs/wave = cap).
// P = exp2(S - 64); no max tracking, no cross-lane ops in the P-path.
// The 2-barrier, late-prefetch schedule is the ONLY variant that fits the
// register budget (R14: DMA-linear -> 3x bank conflicts; R15: hoisted
// loads -> spill; both regressed ~40 us). Do not touch.
// Partials: ks 0/1 -> Op01; ks 2/3 packed in out's f32 slots.
// ---------------------------------------------------------------------------
__global__ __launch_bounds__(256, 2)
void attn_kernel(const short* __restrict__ Qb, const short* __restrict__ Kb,
                 const short* __restrict__ Vb,
                 short* __restrict__ Op01, short* __restrict__ Op23,
                 float* __restrict__ ms)
{
    int bid0 = blockIdx.x;
    int swz = (bid0 & 7) * 64 + (bid0 >> 3);   // XCD swizzle: 64 blocks/XCD
    int b  = swz >> 7;                          // share one (b, 2 ks) K/V set
    int ks = (swz >> 5) & 3;
    int qt = swz & 31;
    int i0 = qt * 128;

    int t = threadIdx.x;
    int wv = t >> 6;
    int lane = t & 63;
    int il = lane & 31, hi = lane >> 5;
    int q0 = i0 + wv * 32;

    __shared__ __align__(16) short Ksh[32][264];   // 16.9 KB
    __shared__ __align__(16) short Vsh[256][40];   // 20.5 KB

    const short* Qp = Qb + (size_t)b * N_DIM * C_DIM;
    const short* Kp = Kb + (size_t)b * N_DIM * C_DIM + (size_t)(ks * 1024) * C_DIM;
    const short* Vp = Vb + (size_t)b * C_DIM * N_DIM + ks * 1024;

    // Q fragments: B[k=c][col=q], lane holds q = q0+il, c = kk*16+hi*8+e
    s16x8 qf[16];
    {
        const short* qrow = Qp + (size_t)(q0 + il) * C_DIM + hi * 8;
        #pragma unroll
        for (int kk = 0; kk < 16; ++kk)
            qf[kk] = *(const s16x8*)&qrow[kk * 16];
    }

    // staging maps (256 threads): K tile 32x256, V tile 256x32, 4x16B each
    int krb = t >> 5, kck = t & 31;   // K rows p*8+krb
    int vrb = t >> 2, vck = t & 3;    // V rows p*64+vrb

    // prologue: stage tile 0
    {
        s16x8 kr[4], vr[4];
        #pragma unroll
        for (int p = 0; p < 4; ++p)
            kr[p] = *(const s16x8*)&Kp[(size_t)(p * 8 + krb) * C_DIM + kck * 8];
        #pragma unroll
        for (int p = 0; p < 4; ++p)
            vr[p] = *(const s16x8*)&Vp[(size_t)(p * 64 + vrb) * N_DIM + vck * 8];
        #pragma unroll
        for (int p = 0; p < 4; ++p) *(s16x8*)&Ksh[p * 8 + krb][kck * 8] = kr[p];
        #pragma unroll
        for (int p = 0; p < 4; ++p) *(s16x8*)&Vsh[p * 64 + vrb][vck * 8] = vr[p];
    }
    __syncthreads();

    f32x16 acc[8] = {};               // O^T[c = cs*32+crow(r,hi)][q = il]
    float srun = 0.f;                 // per-lane partial; reduced in epilogue

    for (int jt = 0; jt < 32; ++jt) {
        bool pfch = (jt < 31);

        // ---- QK: 2 independent 8-chains --------------------------------
        f32x16 sv0 = {}, sv1 = {};
        __builtin_amdgcn_s_setprio(1);
        #pragma unroll
        for (int kk = 0; kk < 8; ++kk) {
            s16x8 a0 = *(const s16x8*)&Ksh[il][kk * 16 + hi * 8];
            sv0 = __builtin_amdgcn_mfma_f32_32x32x16_bf16(a0, qf[kk], sv0, 0, 0, 0);
            s16x8 a1 = *(const s16x8*)&Ksh[il][(kk + 8) * 16 + hi * 8];
            sv1 = __builtin_amdgcn_mfma_f32_32x32x16_bf16(a1, qf[kk + 8], sv1, 0, 0, 0);
        }
        __builtin_amdgcn_s_setprio(0);

        // issue K prefetch (latency hides under softmax+PV)
        s16x8 kr[4];
        if (pfch) {
            const short* kg = Kp + (size_t)((jt + 1) * 32) * C_DIM;
            #pragma unroll
            for (int p = 0; p < 4; ++p)
                kr[p] = *(const s16x8*)&kg[(size_t)(p * 8 + krb) * C_DIM + kck * 8];
        }

        // ---- constant-shift softmax: no max, no rescale, no cross-lane --
        #pragma unroll
        for (int r = 0; r < 16; ++r) {
            float pe = exp2f((sv0[r] + sv1[r]) - 64.f);  // Q pre-scaled log2e
            sv0[r] = pe;
            srun += pe;
        }

        // ---- P -> bf16 PV B-fragments (cvt_pk + permlane32_swap) --------
        unsigned d0[4], d1[4];
        #pragma unroll
        for (int rq = 0; rq < 4; ++rq) {
            d0[rq] = cvtpk(sv0[4 * rq + 0], sv0[4 * rq + 1]);
            d1[rq] = cvtpk(sv0[4 * rq + 2], sv0[4 * rq + 3]);
        }
        unsigned w0a = d0[0], w2a = d0[1]; plswap(w0a, w2a);
        unsigned w1a = d1[0], w3a = d1[1]; plswap(w1a, w3a);
        unsigned w0b = d0[2], w2b = d0[3]; plswap(w0b, w2b);
        unsigned w1b = d1[2], w3b = d1[3]; plswap(w1b, w3b);
        i32x4 pi0 = { (int)w0a, (int)w1a, (int)w2a, (int)w3a };
        i32x4 pi1 = { (int)w0b, (int)w1b, (int)w2b, (int)w3b };
        s16x8 pf0 = __builtin_bit_cast(s16x8, pi0);   // keys 0..15 of tile
        s16x8 pf1 = __builtin_bit_cast(s16x8, pi1);   // keys 16..31

        // issue V prefetch
        s16x8 vr[4];
        if (pfch) {
            const short* vg = Vp + (jt + 1) * 32;
            #pragma unroll
            for (int p = 0; p < 4; ++p)
                vr[p] = *(const s16x8*)&vg[(size_t)(p * 64 + vrb) * N_DIM + vck * 8];
        }

        // ---- PV: 8 c-strips x 2 k-slices, 8 independent acc chains ------
        __builtin_amdgcn_s_setprio(1);
        #pragma unroll
        for (int cs = 0; cs < 8; ++cs) {
            s16x8 va = *(const s16x8*)&Vsh[cs * 32 + il][hi * 8];
            acc[cs] = __builtin_amdgcn_mfma_f32_32x32x16_bf16(va, pf0, acc[cs], 0, 0, 0);
            s16x8 vb = *(const s16x8*)&Vsh[cs * 32 + il][16 + hi * 8];
            acc[cs] = __builtin_amdgcn_mfma_f32_32x32x16_bf16(vb, pf1, acc[cs], 0, 0, 0);
        }
        __builtin_amdgcn_s_setprio(0);

        __syncthreads();                 // all reads of tile jt done
        if (pfch) {
            #pragma unroll
            for (int p = 0; p < 4; ++p) *(s16x8*)&Ksh[p * 8 + krb][kck * 8] = kr[p];
            #pragma unroll
            for (int p = 0; p < 4; ++p) *(s16x8*)&Vsh[p * 64 + vrb][vck * 8] = vr[p];
        }
        __syncthreads();                 // tile jt+1 staged
    }

    // ---- epilogue: reduce srun once; unnormalized O^T partial + s -------
    srun += __shfl_xor(srun, 32, 64);
    int i = q0 + il;
    const size_t HSZ = (size_t)B_DIM * C_DIM * N_DIM;
    if (ks < 2) {
        short* o = Op01 + (size_t)ks * HSZ + (size_t)(b * C_DIM) * N_DIM + i;
        #pragma unroll
        for (int cs = 0; cs < 8; ++cs)
            #pragma unroll
            for (int r = 0; r < 16; ++r) {
                int c = cs * 32 + (r & 3) + 8 * (r >> 2) + 4 * hi;
                o[(size_t)c * N_DIM] = f2bs(acc[cs][r]);
            }
    } else {
        // pack as bf16 pair inside out's f32 slot: [2*idx + (ks-2)]
        short* o = Op23 + ((size_t)(b * C_DIM) * N_DIM + i) * 2 + (ks - 2);
        #pragma unroll
        for (int cs = 0; cs < 8; ++cs)
            #pragma unroll
            for (int r = 0; r < 16; ++r) {
                int c = cs * 32 + (r & 3) + 8 * (r >> 2) + 4 * hi;
                o[(size_t)c * N_DIM * 2] = f2bs(acc[cs][r]);
            }
    }
    if (hi == 0) {
        float* msp = ms + (size_t)(ks * B_DIM + b) * N_DIM;
        msp[i] = srun;
    }
}

// ---------------------------------------------------------------------------
// Kernel 3: 4-way merge + gamma/residual epilogue (BW-bound at ~67 MB ≈ its
// HBM floor). All partials share shift 64 -> plain sums:
// out = g * (sum O_h) / (sum s_h) + x. Op2/3 are read from out's own f32
// slots and overwritten by the SAME thread -> race-free.
// ---------------------------------------------------------------------------
__global__ __launch_bounds__(256)
void merge_kernel(const short* __restrict__ Op01, const short* Op23,
                  const float* __restrict__ ms, const float* __restrict__ x,
                  const float* __restrict__ gamma, float* out)
{
    size_t base = ((size_t)blockIdx.x * 256 + threadIdx.x) * 8;
    int n = (int)(base & (N_DIM - 1));
    int b = (int)(base >> 20);                     // 256*4096 = 2^20 per batch
    const size_t HSZ = (size_t)B_DIM * C_DIM * N_DIM;

    s16x8 o0 = *(const s16x8*)&Op01[base];
    s16x8 o1 = *(const s16x8*)&Op01[HSZ + base];
    s16x8 pa = *(const s16x8*)&Op23[base * 2];      // n..n+3 (o2,o3 pairs)
    s16x8 pb = *(const s16x8*)&Op23[base * 2 + 8];  // n+4..n+7

    f32x4 den[2] = {};
    #pragma unroll
    for (int h = 0; h < 4; ++h) {
        const float* msp = ms + (size_t)(h * B_DIM + b) * N_DIM + n;
        f32x4 sa = *(const f32x4*)&msp[0];
        f32x4 sb = *(const f32x4*)&msp[4];
        #pragma unroll
        for (int e = 0; e < 4; ++e) { den[0][e] += sa[e]; den[1][e] += sb[e]; }
    }
    f32x4 xa = *(const f32x4*)&x[base];
    f32x4 xb = *(const f32x4*)&x[base + 4];
    float g = gamma[0];

    float res[8];
    #pragma unroll
    for (int e = 0; e < 8; ++e) {
        int half = e >> 2, e4 = e & 3;
        float o2 = bs2f(e < 4 ? pa[2 * e]     : pb[2 * (e - 4)]);
        float o3 = bs2f(e < 4 ? pa[2 * e + 1] : pb[2 * (e - 4) + 1]);
        float num = bs2f(o0[e]) + bs2f(o1[e]) + o2 + o3;
        float xv = (e < 4) ? xa[e4] : xb[e4];
        res[e] = g * (num / den[half][e4]) + xv;
    }
    f32x4 ra = { res[0], res[1], res[2], res[3] };
    f32x4 rb = { res[4], res[5], res[6], res[7] };
    *(f32x4*)&out[base] = ra;
    *(f32x4*)&out[base + 4] = rb;
}

// ---------------------------------------------------------------------------
extern "C" void kernel_launch(void* const* d_in, const int* in_sizes, int n_in,
                              void* d_out, int out_size, void* d_ws, size_t ws_size,
                              hipStream_t stream) {
    const float* x  = (const float*)d_in[0];
    const float* y  = (const float*)d_in[1];
    const float* wq = (const float*)d_in[2];
    const float* wk = (const float*)d_in[3];
    const float* wv = (const float*)d_in[4];
    const float* gm = (const float*)d_in[5];
    float* out = (float*)d_out;

    char* ws = (char*)d_ws;
    const size_t SZ = (size_t)B_DIM * N_DIM * C_DIM * sizeof(short); // 8 MB
    short* Qb = (short*)(ws + 2 * SZ);
    short* Kb = (short*)(ws + 3 * SZ);
    short* Vb = (short*)(ws + 4 * SZ);
    // overlays: Op01 -> first 2*SZ of ws (16.8 MB scratch);
    // ms -> ws + 5*SZ (256 KB)
    short* Op01 = (short*)ws;
    float* ms = (float*)(ws + 5 * SZ);

    proj_kernel<<<dim3(512), dim3(256), 0, stream>>>(x, y, wq, wk, wv, Qb, Kb, Vb);
    attn_kernel<<<dim3(512), dim3(256), 0, stream>>>(Qb, Kb, Vb, Op01, (short*)out, ms);
    merge_kernel<<<dim3(2048), dim3(256), 0, stream>>>(Op01, (const short*)out, ms, x, gm, out);
}